// Round 12
// baseline (1963.092 us; speedup 1.0000x reference)
//
#include <hip/hip_runtime.h>
#include <float.h>
#include <math.h>

// Problem constants (fixed by the reference: N=8192, D=512, k+1=31).
#define NN 8192
#define DD 512
#define TOPK 31
#define D3 1.0e-4f       // sound |exact-chain - 3-term MFMA| bound
#define MM 4             // summary slots per 64-col half-tile
#define NHT 128          // half-tiles per row (8192/64)
#define KEXT 48          // 31 + 17 extra band rounds cap
#define NTILE 64         // 8192/128
#define NTRI (NTILE * (NTILE + 1) / 2)  // 2080 upper-tri tiles

// Strategy (R12):
//   Bit-exact value chain (absmax 0.0 R3..R8):
//     h = relu(f*W1)*W2 ; n = sqrtf(numpy-pairwise sum h*h) ; e = h/n
//     sim[i][j] = sequential-k fmaf chain ; stable top-31 (ties -> lower idx)
//   Single 3-term bf16 MFMA GEMM (hh+lh+hl, |err|<=D3), upper-tri tiles.
//   Epilogue: per (row, 64-col half-tile) top-4 packed keys
//   (ordmap(val)<<32 | (8191-idx)) -> TS. Mirror side handled per-column.
//   combine (wave/row): top-31 by key over the 512 stored keys = true approx
//   top-31 IF validation passes: every half-tile's 4th-best < Tc=a31-2*D3
//   (else an unstored 5th could matter -> flag -> exact cleanup).
//   Extras >= Tc collected; exact chains re-rank the band; write zeros+vals.

typedef __attribute__((ext_vector_type(8))) short short8;
typedef __attribute__((ext_vector_type(4))) float f32x4;

__device__ __forceinline__ float h_elem(const float* __restrict__ f,
                                        const float* __restrict__ W1,
                                        const float* __restrict__ W2, int k) {
  float x = f[k] * W1[k];
  x = fmaxf(x, 0.0f);
  return x * W2[k];
}

__device__ __forceinline__ unsigned short f2bf_rne(float x) {
  unsigned u = __float_as_uint(x);
  unsigned r = (u >> 16) & 1u;
  u += 0x7fffu + r;
  return (unsigned short)(u >> 16);
}
__device__ __forceinline__ float bf2f(unsigned short h) {
  return __uint_as_float(((unsigned)h) << 16);
}
__device__ __forceinline__ unsigned ordmap(float x) {
  unsigned u = __float_as_uint(x);
  return (u & 0x80000000u) ? ~u : (u | 0x80000000u);
}
__device__ __forceinline__ float ordunmap(unsigned u) {
  return __uint_as_float((u & 0x80000000u) ? (u & 0x7fffffffu) : ~u);
}

// async global->LDS, 16 B/lane; LDS dest = wave-uniform base + lane*16
__device__ __forceinline__ void gl_lds16(const unsigned short* g,
                                         unsigned short* l) {
  __builtin_amdgcn_global_load_lds(
      (const __attribute__((address_space(1))) unsigned int*)g,
      (__attribute__((address_space(3))) unsigned int*)l, 16, 0, 0);
}

__device__ __forceinline__ void tri_decode(int s, int& bx, int& by) {
  int b = 0;
  while (s >= NTILE - b) {
    s -= NTILE - b;
    ++b;
  }
  by = b;
  bx = b + s;
}

// ---------------------------------------------------------------------------
// Kernel A: fused norm (numpy pairwise association, bit-exact) + e = h/n,
// bf16 hi/lo split, flag zeroing. One wave per row.
// ---------------------------------------------------------------------------
__global__ __launch_bounds__(256) void emb_kernel(
    const float* __restrict__ f, const float* __restrict__ W1,
    const float* __restrict__ W2, float* __restrict__ e32,
    unsigned short* __restrict__ Ehi, unsigned short* __restrict__ Elo,
    int* __restrict__ flags) {
  const int lane = threadIdx.x & 63;
  const int row = blockIdx.x * 4 + (threadIdx.x >> 6);
  const float* fr = f + (size_t)row * DD;
  const int b = lane >> 4, L = lane & 15;
  if (lane == 0) flags[row] = 0;

  float s[8];
#pragma unroll
  for (int j = 0; j < 8; ++j) {
    float h = h_elem(fr, W1, W2, b * 128 + 16 * j + L);
    s[j] = h * h;
  }
  float v = ((s[0] + s[1]) + (s[2] + s[3])) + ((s[4] + s[5]) + (s[6] + s[7]));
  float t = v + __shfl_xor(v, 8);
  t = t + __shfl_xor(t, 4);
  t = t + __shfl_xor(t, 2);
  float nb = t + __shfl_xor(t, 1);
  float x = nb + __shfl_xor(nb, 16);
  float norm2 = x + __shfl_xor(x, 32);
  const float n = fmaxf(sqrtf(norm2), 1e-12f);

  float* er = e32 + (size_t)row * DD;
  unsigned short* hr = Ehi + (size_t)row * DD;
  unsigned short* lr = Elo + (size_t)row * DD;
#pragma unroll
  for (int m = 0; m < 8; ++m) {
    int k = m * 64 + lane;
    float e = h_elem(fr, W1, W2, k) / n;
    er[k] = e;
    unsigned short hb = f2bf_rne(e);
    hr[k] = hb;
    lr[k] = f2bf_rne(e - bf2f(hb));
  }
}

// ---------------------------------------------------------------------------
// Kernel B: 3-term bf16 MFMA GEMM (hh + lh + hl), triangular grid, BK=32,
// 32 KB LDS layout v2 (chunk q = part*128 + row -> 2-way conflicts only).
// Epilogue: per-row (and mirrored per-col) top-4 packed keys -> TS.
// ---------------------------------------------------------------------------
__global__ __launch_bounds__(256) void gemm3_sum(
    const unsigned short* __restrict__ Ehi,
    const unsigned short* __restrict__ Elo,
    unsigned long long* __restrict__ TS) {
  int bx, by;
  tri_decode(blockIdx.x, bx, by);
  __shared__ __align__(16) unsigned short S[4 * 4096];  // 32 KB
  const int t = threadIdx.x;
  const int lane = t & 63, w = t >> 6;
  const int wr = w >> 1, wc = w & 1;
  const int quad = lane >> 4, l16 = lane & 15;
  const int i0 = by * 128, j0 = bx * 128;

  f32x4 acc[4][4];
#pragma unroll
  for (int a = 0; a < 4; ++a)
#pragma unroll
    for (int b = 0; b < 4; ++b) acc[a][b] = (f32x4){0.f, 0.f, 0.f, 0.f};

  for (int kk = 0; kk < DD; kk += 32) {
    __syncthreads();
#pragma unroll
    for (int c = 0; c < 2; ++c) {
      int q = c * 256 + t;  // chunk in [0,512): r=q&127, p=q>>7
      int r = q & 127, p = q >> 7;
      size_t ga = (size_t)(i0 + r) * DD + kk + p * 8;
      size_t gb = (size_t)(j0 + r) * DD + kk + p * 8;
      gl_lds16(&Ehi[ga], &S[q * 8]);           // AH
      gl_lds16(&Elo[ga], &S[4096 + q * 8]);    // AL
      gl_lds16(&Ehi[gb], &S[8192 + q * 8]);    // BH
      gl_lds16(&Elo[gb], &S[12288 + q * 8]);   // BL
    }
    __syncthreads();
    short8 ah[4], al[4], bh[4], bl[4];
#pragma unroll
    for (int mt = 0; mt < 4; ++mt) {
      int R = wr * 64 + mt * 16 + l16;
      int off = (quad * 128 + R) * 8;
      ah[mt] = *(const short8*)&S[off];
      al[mt] = *(const short8*)&S[4096 + off];
    }
#pragma unroll
    for (int nt = 0; nt < 4; ++nt) {
      int R = wc * 64 + nt * 16 + l16;
      int off = (quad * 128 + R) * 8;
      bh[nt] = *(const short8*)&S[8192 + off];
      bl[nt] = *(const short8*)&S[12288 + off];
    }
#pragma unroll
    for (int mt = 0; mt < 4; ++mt)
#pragma unroll
      for (int nt = 0; nt < 4; ++nt)
        acc[mt][nt] = __builtin_amdgcn_mfma_f32_16x16x32_bf16(
            ah[mt], bh[nt], acc[mt][nt], 0, 0, 0);
#pragma unroll
    for (int mt = 0; mt < 4; ++mt)
#pragma unroll
      for (int nt = 0; nt < 4; ++nt)
        acc[mt][nt] = __builtin_amdgcn_mfma_f32_16x16x32_bf16(
            al[mt], bh[nt], acc[mt][nt], 0, 0, 0);
#pragma unroll
    for (int mt = 0; mt < 4; ++mt)
#pragma unroll
      for (int nt = 0; nt < 4; ++nt)
        acc[mt][nt] = __builtin_amdgcn_mfma_f32_16x16x32_bf16(
            ah[mt], bl[nt], acc[mt][nt], 0, 0, 0);
  }

  // --- epilogue 1: per-ROW top-4 of this wave's 64 cols (C/D layout:
  //     col = l16 (+nt*16), row = quad*4 + r (+mt*16)). 16-lane group argmax.
  const int htb = bx * 2 + wc;
#pragma unroll
  for (int mt = 0; mt < 4; ++mt)
#pragma unroll
    for (int r = 0; r < 4; ++r) {
      const int grow = i0 + wr * 64 + mt * 16 + quad * 4 + r;
      unsigned msk = 0xFu;
#pragma unroll
      for (int s = 0; s < MM; ++s) {
        float lv = -FLT_MAX;
        int ln = 0;
#pragma unroll
        for (int nt = 0; nt < 4; ++nt) {
          float vv = acc[mt][nt][r];
          if (((msk >> nt) & 1) && vv > lv) { lv = vv; ln = nt; }
        }
        // tie -> smaller col (ln*16+l16): encode 63 - (ln*16+l16)
        unsigned long long key =
            ((unsigned long long)ordmap(lv) << 32) |
            (unsigned)(63 - (ln * 16 + l16));
#pragma unroll
        for (int off = 1; off < 16; off <<= 1) {
          unsigned long long o = __shfl_xor(key, off);
          if (o > key) key = o;
        }
        int cm = 63 - (int)(key & 63u);
        int wl = cm & 15, wn = cm >> 4;
        int gcol = j0 + wc * 64 + wn * 16 + wl;
        unsigned long long st =
            (key & 0xFFFFFFFF00000000ull) | (unsigned)(8191 - gcol);
        if (l16 == s) TS[(size_t)grow * (NHT * MM) + htb * MM + s] = st;
        if (l16 == wl) msk &= ~(1u << wn);
      }
    }

  // --- epilogue 2 (off-diagonal): per-COL top-4 of this wave's 64 rows.
  if (bx > by) {
    const int htm = by * 2 + wr;
#pragma unroll
    for (int nt = 0; nt < 4; ++nt) {
      // lane-local sorted top-4 of 16 values; tie -> smaller local row li
      unsigned long long loc0 = 0, loc1 = 0, loc2 = 0, loc3 = 0;
#pragma unroll
      for (int mt = 0; mt < 4; ++mt)
#pragma unroll
        for (int r = 0; r < 4; ++r) {
          int li = wr * 64 + mt * 16 + quad * 4 + r;
          unsigned long long kk =
              ((unsigned long long)ordmap(acc[mt][nt][r]) << 32) |
              (unsigned)(127 - li);
          if (kk > loc0) { unsigned long long tm = loc0; loc0 = kk; kk = tm; }
          if (kk > loc1) { unsigned long long tm = loc1; loc1 = kk; kk = tm; }
          if (kk > loc2) { unsigned long long tm = loc2; loc2 = kk; kk = tm; }
          if (kk > loc3) { loc3 = kk; }
        }
      const int gcol = j0 + wc * 64 + nt * 16 + l16;
#pragma unroll
      for (int s = 0; s < MM; ++s) {
        unsigned long long cand = loc0;
        unsigned long long mx = cand;
#pragma unroll
        for (int off = 16; off < 64; off <<= 1) {
          unsigned long long o = __shfl_xor(mx, off);
          if (o > mx) mx = o;
        }
        int li = 127 - (int)(mx & 127u);
        int grow2 = i0 + li;
        unsigned long long st =
            (mx & 0xFFFFFFFF00000000ull) | (unsigned)(8191 - grow2);
        if (quad == s) TS[(size_t)gcol * (NHT * MM) + htm * MM + s] = st;
        if (cand == mx) { loc0 = loc1; loc1 = loc2; loc2 = loc3; loc3 = 0; }
      }
    }
  }
}

// ---------------------------------------------------------------------------
// Kernel C: combine — one WAVE per row, zero block barriers.
// Top-31 by packed key over the 512 stored keys; validate coverage; extras
// >= Tc; exact chains re-rank the band; write zeros + relu(values).
// ---------------------------------------------------------------------------
__global__ __launch_bounds__(256) void combine(
    float* __restrict__ C, const float* __restrict__ e32,
    const unsigned long long* __restrict__ TS, int* __restrict__ flags) {
  const int w = threadIdx.x >> 6;
  const int lane = threadIdx.x & 63;
  const int row = blockIdx.x * 4 + w;

  __shared__ float er[4][DD];                      // 8 KB
  __shared__ unsigned long long bmap[4][NN / 64];  // 4 KB
  __shared__ int kidxL[4][TOPK];
  __shared__ float kvalL[4][TOPK];
  __shared__ int exI[4][KEXT - TOPK];
  __shared__ float exV[4][KEXT - TOPK];
  __shared__ int bndI[4][KEXT];
  __shared__ float bndV[4][KEXT];
  __shared__ float bndE[4][KEXT];

  unsigned long long K[8];
  const unsigned long long* Tr = TS + (size_t)row * (NHT * MM);
#pragma unroll
  for (int s = 0; s < 8; ++s) K[s] = Tr[s * 64 + lane];

  {
    const float4* e4 = (const float4*)(e32 + (size_t)row * DD);
    float4* er4 = (float4*)er[w];
    er4[lane] = e4[lane];
    er4[64 + lane] = e4[64 + lane];
  }
#pragma unroll
  for (int q = 0; q < 2; ++q) bmap[w][q * 64 + lane] = 0ull;

  unsigned taken = 0;
  float a31 = 0.f;
  int be = 0;
  bool stopped = false;

  for (int it = 0; it < KEXT; ++it) {
    unsigned long long best = 0ull;
    int bs = -1;
#pragma unroll
    for (int s = 0; s < 8; ++s)
      if (!((taken >> s) & 1) && K[s] > best) { best = K[s]; bs = s; }
    unsigned long long mx = best;
#pragma unroll
    for (int off = 1; off < 64; off <<= 1) {
      unsigned long long o = __shfl_xor(mx, off);
      if (o > mx) mx = o;
    }
    float val = ordunmap((unsigned)(mx >> 32));
    int idx = 8191 - (int)(mx & 0xFFFFFFFFull);
    if (it < TOPK) {
      if (best == mx && bs >= 0) taken |= 1u << bs;
      if (lane == 0) { kidxL[w][it] = idx; kvalL[w][it] = val; }
      if (it == TOPK - 1) a31 = val;
    } else {
      if (val >= a31 - 2.0f * D3) {
        if (best == mx && bs >= 0) taken |= 1u << bs;
        if (lane == 0) { exI[w][be] = idx; exV[w][be] = val; }
        ++be;
      } else {
        stopped = true;
        break;
      }
    }
  }

  // validation: any half-tile's 4th-best >= Tc means possible unstored cand
  const float Tc = a31 - 2.0f * D3;
  bool bad = !stopped;  // ran out of extra rounds: can't bound the band
  if ((lane & 3) == 3) {
#pragma unroll
    for (int s = 0; s < 8; ++s) {
      float v2 = ordunmap((unsigned)(K[s] >> 32));
      if (v2 >= Tc) bad = true;
    }
  }
  if (__ballot(bad) != 0ull) {
    if (lane == 0) flags[row] = 1;
    return;
  }

  if (be > 0) {
    // m = prefix count of sure-ins (sorted desc => prefix property)
    bool pre = (lane < TOPK) && (kvalL[w][lane] > a31 + 2.0f * D3);
    unsigned long long bal = __ballot(pre);
    int m = __popcll(bal);
    int nb = (TOPK - m) + be;  // <= 48
    if (lane < nb) {
      if (lane < TOPK - m) {
        bndI[w][lane] = kidxL[w][m + lane];
        bndV[w][lane] = kvalL[w][m + lane];
      } else {
        bndI[w][lane] = exI[w][lane - (TOPK - m)];
        bndV[w][lane] = exV[w][lane - (TOPK - m)];
      }
    }
    // exact sequential-k fmaf chains (bit-identical to the verified chain)
    if (lane < nb) {
      const float4* ej4 = (const float4*)(e32 + (size_t)bndI[w][lane] * DD);
      float a = 0.f;
      for (int k4 = 0; k4 < DD / 4; ++k4) {
        float4 vv = ej4[k4];
        const float* e = &er[w][k4 * 4];
        a = fmaf(e[0], vv.x, a);
        a = fmaf(e[1], vv.y, a);
        a = fmaf(e[2], vv.z, a);
        a = fmaf(e[3], vv.w, a);
      }
      bndE[w][lane] = a;
    }
    // re-rank band by (exact desc, idx asc); overwrite slots m..30
    if (lane < nb) {
      float ce = bndE[w][lane];
      int idx = bndI[w][lane];
      int rk = 0;
      for (int q = 0; q < nb; ++q) {
        float c2 = bndE[w][q];
        if (c2 > ce || (c2 == ce && bndI[w][q] < idx)) ++rk;
      }
      if (rk < TOPK - m) {
        kidxL[w][m + rk] = idx;
        kvalL[w][m + rk] = bndV[w][lane];
      }
    }
  }

  if (lane < TOPK) {
    int idx = kidxL[w][lane];
    atomicOr(&bmap[w][idx >> 6], 1ull << (idx & 63));
    kvalL[w][lane] = fmaxf(kvalL[w][lane], 0.f);  // relu
  }

  // stream-write the output row (0 or kept value)
  float4* Cw4 = (float4*)(C + (size_t)row * NN);
  for (int it = 0; it < 32; ++it) {
    int j4 = (it * 64 + lane) * 4;
    float4 o = make_float4(0.f, 0.f, 0.f, 0.f);
    unsigned long long word = bmap[w][j4 >> 6];
    unsigned nib = (unsigned)((word >> (j4 & 63)) & 0xFull);
    if (nib) {
#pragma unroll
      for (int c = 0; c < 4; ++c)
        if ((nib >> c) & 1u) {
          int j = j4 + c;
          float val = 0.f;
          for (int s = 0; s < TOPK; ++s)
            if (kidxL[w][s] == j) val = kvalL[w][s];
          ((float*)&o)[c] = val;
        }
    }
    Cw4[it * 64 + lane] = o;
  }
}

// ---------------------------------------------------------------------------
// Kernel D: exact cleanup for flagged rows (expected ~150 rows).
// ---------------------------------------------------------------------------
__global__ __launch_bounds__(256) void cleanup_kernel(
    float* __restrict__ C, const float* __restrict__ e32,
    const int* __restrict__ flags) {
  const int row = blockIdx.x;
  if (flags[row] == 0) return;
  const int tid = threadIdx.x;
  const int lane = tid & 63, wid = tid >> 6;

  __shared__ float sv[NN];
  __shared__ float er[DD];
  __shared__ unsigned long long wred[4];
  __shared__ int kidx[TOPK];
  __shared__ float kval[TOPK];

  {
    const float4* e4 = (const float4*)(e32 + (size_t)row * DD);
    if (tid < DD / 4) ((float4*)er)[tid] = e4[tid];
  }
  __syncthreads();

  for (int m = 0; m < NN / 256; ++m) {
    int j = m * 256 + tid;
    const float* ej = e32 + (size_t)j * DD;
    float a = 0.f;
    for (int k = 0; k < DD; k += 4) {
      float4 v = *(const float4*)&ej[k];
      a = fmaf(er[k], v.x, a);
      a = fmaf(er[k + 1], v.y, a);
      a = fmaf(er[k + 2], v.z, a);
      a = fmaf(er[k + 3], v.w, a);
    }
    sv[j] = a;
  }
  __syncthreads();

  for (int it = 0; it < TOPK; ++it) {
    float bv = -FLT_MAX;
    int bi = 0;
    for (int j = tid; j < NN; j += 256) {
      float v = sv[j];
      if (v > bv) { bv = v; bi = j; }
    }
    unsigned long long key =
        ((unsigned long long)ordmap(bv) << 32) | (unsigned)(NN - 1 - bi);
#pragma unroll
    for (int off = 32; off; off >>= 1) {
      unsigned long long o = __shfl_xor(key, off);
      if (o > key) key = o;
    }
    if (lane == 0) wred[wid] = key;
    __syncthreads();
    if (tid == 0) {
      unsigned long long k0 = wred[0];
      if (wred[1] > k0) k0 = wred[1];
      if (wred[2] > k0) k0 = wred[2];
      if (wred[3] > k0) k0 = wred[3];
      int idx = (NN - 1) - (int)(k0 & 0xFFFFFFFFu);
      kidx[it] = idx;
      kval[it] = sv[idx];
      sv[idx] = -FLT_MAX;
    }
    __syncthreads();
  }

  float4 z4 = make_float4(0.f, 0.f, 0.f, 0.f);
  float4* sv4 = (float4*)sv;
  for (int i = tid; i < NN / 4; i += 256) sv4[i] = z4;
  __syncthreads();
  if (tid < TOPK) sv[kidx[tid]] = fmaxf(kval[tid], 0.0f);
  __syncthreads();
  float4* Cw4 = (float4*)(C + (size_t)row * NN);
  for (int i = tid; i < NN / 4; i += 256) Cw4[i] = sv4[i];
}

// ---------------------------------------------------------------------------
extern "C" void kernel_launch(void* const* d_in, const int* in_sizes, int n_in,
                              void* d_out, int out_size, void* d_ws,
                              size_t ws_size, hipStream_t stream) {
  const float* f = (const float*)d_in[0];
  const float* W1 = (const float*)d_in[1];
  const float* W2 = (const float*)d_in[2];
  float* out = (float*)d_out;
  char* ws = (char*)d_ws;
  const size_t MB = 1024 * 1024;
  float* e32 = (float*)ws;                                        // 16 MiB
  unsigned short* Ehi = (unsigned short*)(ws + 16 * MB);          // 8 MiB
  unsigned short* Elo = (unsigned short*)(ws + 24 * MB);          // 8 MiB
  unsigned long long* TS = (unsigned long long*)(ws + 32 * MB);   // 32 MiB
  int* flags = (int*)(ws + 64 * MB);                              // 32 KB

  emb_kernel<<<NN / 4, 256, 0, stream>>>(f, W1, W2, e32, Ehi, Elo, flags);
  gemm3_sum<<<NTRI, 256, 0, stream>>>(Ehi, Elo, TS);
  combine<<<NN / 4, 256, 0, stream>>>(out, e32, TS, flags);
  cleanup_kernel<<<NN, 256, 0, stream>>>(out, e32, flags);
}